// Round 4
// baseline (416.666 us; speedup 1.0000x reference)
//
#include <hip/hip_runtime.h>
#include <hip/hip_bf16.h>
#include <stdint.h>

#define BATCH 8
#define SEQ 2048
#define DMODEL 1024

typedef __attribute__((ext_vector_type(4))) float f32x4;
typedef __attribute__((ext_vector_type(8))) short bf16x8;
typedef __attribute__((ext_vector_type(4))) uint32_t u32x4;
typedef __attribute__((ext_vector_type(2))) uint32_t u32x2;

#define MFMA16(a, b, c) __builtin_amdgcn_mfma_f32_16x16x32_bf16((a), (b), (c), 0, 0, 0)

static __device__ __forceinline__ uint16_t f2bf(float f) {
    uint32_t u = __builtin_bit_cast(uint32_t, f);
    u += 0x7fffu + ((u >> 16) & 1u);   // round-to-nearest-even
    return (uint16_t)(u >> 16);
}
static __device__ __forceinline__ uint32_t pk2(float lo, float hi) {
    return (uint32_t)f2bf(lo) | ((uint32_t)f2bf(hi) << 16);
}
// async global->LDS, 16B per lane. LDS dest is wave-uniform base + lane*16.
static __device__ __forceinline__ void gload16(const uint16_t* g, uint16_t* l) {
    __builtin_amdgcn_global_load_lds((const __attribute__((address_space(1))) void*)g,
                                     (__attribute__((address_space(3))) void*)l, 16, 0, 0);
}

// ---------------------------------------------------------------------------
// Kernel 0: f32 -> bf16 cast, 8 elems/thread (memory-bound).
// ---------------------------------------------------------------------------
__global__ __launch_bounds__(256) void cast_bf16(const float* __restrict__ src,
                                                 uint16_t* __restrict__ dst) {
    const size_t i = ((size_t)blockIdx.x * 256 + threadIdx.x) * 8;
    f32x4 a = *(const f32x4*)(src + i);
    f32x4 b = *(const f32x4*)(src + i + 4);
    u32x4 o = {pk2(a[0], a[1]), pk2(a[2], a[3]), pk2(b[0], b[1]), pk2(b[2], b[3])};
    *(u32x4*)(dst + i) = o;
}

// ---------------------------------------------------------------------------
// Kernel 1: cast + transpose weights. WT[z][n][k] = W_z[k][n], bf16.
// ---------------------------------------------------------------------------
__global__ void wt_cast_kernel(const float* __restrict__ Wk, const float* __restrict__ Wv,
                               const float* __restrict__ Wq, uint16_t* __restrict__ WT) {
    const float* W = blockIdx.z == 0 ? Wk : (blockIdx.z == 1 ? Wv : Wq);
    uint16_t* dst = WT + (size_t)blockIdx.z * DMODEL * DMODEL;
    __shared__ float tile[32][33];
    const int x = blockIdx.x * 32, y = blockIdx.y * 32;
    const int tx = threadIdx.x, ty = threadIdx.y;
#pragma unroll
    for (int j = 0; j < 4; j++)
        tile[ty * 4 + j][tx] = W[(size_t)(y + ty * 4 + j) * DMODEL + x + tx];
    __syncthreads();
#pragma unroll
    for (int j = 0; j < 4; j++)
        dst[(size_t)(x + ty * 4 + j) * DMODEL + y + tx] = f2bf(tile[tx][ty * 4 + j]);
}

// ---------------------------------------------------------------------------
// Kernel 2: pipelined 256x256 B^T GEMM.  C[b][m][n] = sum_k A[b][m][k]*Bt[b][n][k]
// 8 waves (2Mx4N), BK=32, 3-slot LDS rotation, prefetch depth 2,
// counted vmcnt(8) (never drained in main loop), raw s_barrier, setprio MFMA.
// BX=1: batch on blockIdx.x (fastest) -> XCD = batch: per-XCD working set is
// that batch's panels only (L2-resident) instead of all batches' B panels.
// MODE 0: bf16 C[m][n] * scale.  MODE 1: bf16 V-transpose store out[b][n][s].
// MODE 2: f32 C[m][n] * Linv[row].
// ---------------------------------------------------------------------------
#define STAGE(tile, s)                                        \
    do {                                                      \
        const size_t ko_ = (size_t)(tile) * 32;               \
        gload16(Ab + ko_ + aoff0, &As[s][t * 8]);             \
        gload16(Ab + ko_ + aoff1, &As[s][t * 8 + 4096]);      \
        gload16(Bb + ko_ + boff0, &Bs[s][t * 8]);             \
        gload16(Bb + ko_ + boff1, &Bs[s][t * 8 + 4096]);      \
    } while (0)

#define KBODY(s, WAITSTR)                                                              \
    do {                                                                               \
        asm volatile("s_waitcnt " WAITSTR ::: "memory");                               \
        __builtin_amdgcn_s_barrier();                                                  \
        bf16x8 bfr[4], afr[8];                                                         \
        _Pragma("unroll") for (int j = 0; j < 4; j++)                                  \
            bfr[j] = *(const bf16x8*)&Bs[s][(wc * 64 + j * 16 + lr) * 32 + lg * 8];    \
        _Pragma("unroll") for (int i = 0; i < 8; i++)                                  \
            afr[i] = *(const bf16x8*)&As[s][(wr * 128 + i * 16 + lr) * 32 + lg * 8];   \
        __builtin_amdgcn_s_setprio(1);                                                 \
        _Pragma("unroll") for (int i = 0; i < 4; i++)                                  \
            _Pragma("unroll") for (int j = 0; j < 4; j++)                              \
                acc[i][j] = MFMA16(afr[i], bfr[j], acc[i][j]);                         \
        __builtin_amdgcn_s_setprio(0);                                                 \
        __builtin_amdgcn_s_setprio(1);                                                 \
        _Pragma("unroll") for (int i = 4; i < 8; i++)                                  \
            _Pragma("unroll") for (int j = 0; j < 4; j++)                              \
                acc[i][j] = MFMA16(afr[i], bfr[j], acc[i][j]);                         \
        __builtin_amdgcn_s_setprio(0);                                                 \
        asm volatile("s_waitcnt lgkmcnt(0)" ::: "memory");                             \
        __builtin_amdgcn_sched_barrier(0);                                             \
        __builtin_amdgcn_s_barrier();                                                  \
    } while (0)

template <int MODE, int BX>
__global__ __launch_bounds__(512, 2) void gemm256(const uint16_t* __restrict__ Ag,
                                                  const uint16_t* __restrict__ Bg,
                                                  void* __restrict__ Cg,
                                                  const float* __restrict__ Linv,
                                                  float scale, int lda, int ldb, int ldc,
                                                  int nk, size_t sA, size_t sB, size_t sC) {
    __shared__ __align__(16) uint16_t As[3][256 * 32];
    __shared__ __align__(16) uint16_t Bs[3][256 * 32];
    const int bz = BX ? blockIdx.x : blockIdx.z;
    const int bm = BX ? blockIdx.y : blockIdx.x;
    const int bn = BX ? blockIdx.z : blockIdx.y;
    const int m0 = bm * 256, n0 = bn * 256;
    const uint16_t* Ab = Ag + (size_t)bz * sA + (size_t)m0 * lda;
    const uint16_t* Bb = Bg + (size_t)bz * sB + (size_t)n0 * ldb;
    const int t = threadIdx.x, lane = t & 63;
    const int wid = t >> 6, wr = wid >> 2, wc = wid & 3;
    const int lr = lane & 15, lg = lane >> 4;
    // linear staging: chunk c in {t, t+512}: row = c>>2, 16B-slot = c&3
    const int srow = t >> 2, sslot = t & 3;
    const size_t aoff0 = (size_t)srow * lda + sslot * 8;
    const size_t aoff1 = aoff0 + (size_t)128 * lda;
    const size_t boff0 = (size_t)srow * ldb + sslot * 8;
    const size_t boff1 = boff0 + (size_t)128 * ldb;

    f32x4 acc[8][4] = {};
    STAGE(0, 0);
    STAGE(1, 1);
    int s = 0, s2 = 2;
    for (int kt = 0; kt < nk - 2; ++kt) {
        STAGE(kt + 2, s2);
        KBODY(s, "vmcnt(8)");
        s = (s == 2) ? 0 : s + 1;
        s2 = (s2 == 2) ? 0 : s2 + 1;
    }
    KBODY(s, "vmcnt(4)");
    s = (s == 2) ? 0 : s + 1;
    KBODY(s, "vmcnt(0)");

    if constexpr (MODE == 0) {
        uint16_t* C = (uint16_t*)Cg + (size_t)bz * sC;
#pragma unroll
        for (int i = 0; i < 8; i++) {
            const int gm = m0 + wr * 128 + i * 16 + lg * 4;
#pragma unroll
            for (int j = 0; j < 4; j++) {
                const int gn = n0 + wc * 64 + j * 16 + lr;
#pragma unroll
                for (int r = 0; r < 4; r++)
                    C[(size_t)(gm + r) * ldc + gn] = f2bf(acc[i][j][r] * scale);
            }
        }
    } else if constexpr (MODE == 1) {
        uint16_t* C = (uint16_t*)Cg;
#pragma unroll
        for (int i = 0; i < 8; i++) {
            const int gm = m0 + wr * 128 + i * 16 + lg * 4;  // global m = b*SEQ + s
            const int bb = gm / SEQ;                         // 256 | SEQ: uniform per block
            const int sx = gm - bb * SEQ;
#pragma unroll
            for (int j = 0; j < 4; j++) {
                const int e = n0 + wc * 64 + j * 16 + lr;
                u32x2 v = {pk2(acc[i][j][0], acc[i][j][1]), pk2(acc[i][j][2], acc[i][j][3])};
                *(u32x2*)&C[((size_t)bb * DMODEL + e) * SEQ + sx] = v;
            }
        }
    } else {
        float* C = (float*)Cg + (size_t)bz * sC;
        const float* LB = Linv + bz * SEQ;
#pragma unroll
        for (int i = 0; i < 8; i++) {
            const int gm = m0 + wr * 128 + i * 16 + lg * 4;
            const f32x4 lv = *(const f32x4*)&LB[gm];
#pragma unroll
            for (int j = 0; j < 4; j++) {
                const int gn = n0 + wc * 64 + j * 16 + lr;
#pragma unroll
                for (int r = 0; r < 4; r++)
                    C[(size_t)(gm + r) * ldc + gn] = acc[i][j][r] * lv[r];
            }
        }
    }
}

// ---------------------------------------------------------------------------
// Kernel 3: row softmax, in place.  One block per row (16384 blocks).
// ---------------------------------------------------------------------------
__global__ __launch_bounds__(256) void softmax_rows(uint16_t* __restrict__ S,
                                                    float* __restrict__ Linv) {
    const size_t row = blockIdx.x;
    uint16_t* s = S + row * SEQ;
    const int t = threadIdx.x, lane = t & 63, w = t >> 6;
    __shared__ float redm[4], reds[4];
    u32x4 raw = *(const u32x4*)(s + t * 8);
    float v[8];
#pragma unroll
    for (int j = 0; j < 4; j++) {
        v[2 * j]     = __builtin_bit_cast(float, raw[j] << 16);
        v[2 * j + 1] = __builtin_bit_cast(float, raw[j] & 0xffff0000u);
    }
    float m = v[0];
#pragma unroll
    for (int i = 1; i < 8; i++) m = fmaxf(m, v[i]);
#pragma unroll
    for (int d = 1; d < 64; d <<= 1) m = fmaxf(m, __shfl_xor(m, d));
    if (lane == 0) redm[w] = m;
    __syncthreads();
    m = fmaxf(fmaxf(redm[0], redm[1]), fmaxf(redm[2], redm[3]));
    float p[8], sum = 0.0f;
#pragma unroll
    for (int i = 0; i < 8; i++) { p[i] = __expf(v[i] - m); sum += p[i]; }
#pragma unroll
    for (int d = 1; d < 64; d <<= 1) sum += __shfl_xor(sum, d);
    if (lane == 0) reds[w] = sum;
    __syncthreads();
    sum = reds[0] + reds[1] + reds[2] + reds[3];
    u32x4 outp;
#pragma unroll
    for (int j = 0; j < 4; j++) outp[j] = pk2(p[2 * j], p[2 * j + 1]);
    *(u32x4*)(s + t * 8) = outp;
    if (t == 0) Linv[row] = 1.0f / sum;
}

// ---------------------------------------------------------------------------
// Workspace layout (bytes):
//   Qbf [16384][1024] bf16 :          0   (Q pre-scaled by 1/32)
//   Kbf [16384][1024] bf16 :  33,554,432
//   VTb [8][1024][2048] bf16: 67,108,864
//   WT  [3][1024][1024] bf16:100,663,296
//   Linv[16384] f32        : 106,954,752
//   S/P [8][2048][2048] bf16:107,020,288  (P in place)
//   Xbf [16384][1024] bf16 :171,966,464   (reused for Xq, Xk, Xv in turn)
// ---------------------------------------------------------------------------
extern "C" void kernel_launch(void* const* d_in, const int* in_sizes, int n_in,
                              void* d_out, int out_size, void* d_ws, size_t ws_size,
                              hipStream_t stream) {
    const float* Xk = (const float*)d_in[0];
    const float* Xv = (const float*)d_in[1];
    const float* Xq = (const float*)d_in[2];
    const float* Wk = (const float*)d_in[3];
    const float* Wv = (const float*)d_in[4];
    const float* Wq = (const float*)d_in[5];
    float* out = (float*)d_out;
    char* ws = (char*)d_ws;
    uint16_t* Qbf = (uint16_t*)(ws);
    uint16_t* Kbf = (uint16_t*)(ws + (size_t)33554432);
    uint16_t* VTb = (uint16_t*)(ws + (size_t)67108864);
    uint16_t* WT  = (uint16_t*)(ws + (size_t)100663296);
    float*    Linv= (float*)(ws + (size_t)106954752);
    uint16_t* Sb  = (uint16_t*)(ws + (size_t)107020288);
    uint16_t* Xbf = (uint16_t*)(ws + (size_t)171966464);

    wt_cast_kernel<<<dim3(32, 32, 3), dim3(32, 8), 0, stream>>>(Wk, Wv, Wq, WT);
    // Q projection (scale 1/sqrt(1024) folded into bf16 store). Weights (2 MB)
    // are L2-resident per XCD -> keep m-tile on x here.
    cast_bf16<<<8192, 256, 0, stream>>>(Xq, Xbf);
    gemm256<0, 0><<<dim3(64, 4, 1), 512, 0, stream>>>(
        Xbf, WT + 2 * 1048576, (void*)Qbf, nullptr, 0.03125f,
        DMODEL, DMODEL, DMODEL, DMODEL / 32, 0, 0, 0);
    // K projection
    cast_bf16<<<8192, 256, 0, stream>>>(Xk, Xbf);
    gemm256<0, 0><<<dim3(64, 4, 1), 512, 0, stream>>>(
        Xbf, WT, (void*)Kbf, nullptr, 1.0f,
        DMODEL, DMODEL, DMODEL, DMODEL / 32, 0, 0, 0);
    // V projection with transposed store -> VT[b][e][s]
    cast_bf16<<<8192, 256, 0, stream>>>(Xv, Xbf);
    gemm256<1, 0><<<dim3(64, 4, 1), 512, 0, stream>>>(
        Xbf, WT + 1048576, (void*)VTb, nullptr, 1.0f,
        DMODEL, DMODEL, 0, DMODEL / 32, 0, 0, 0);
    // scores: S[b][q][k] = Qhat[b] . K[b]^T   (bf16 store)
    // batch on blockIdx.x -> XCD = batch: per-XCD working set = Q_b + K_b (8.4 MB)
    gemm256<0, 1><<<dim3(8, 8, 8), 512, 0, stream>>>(
        Qbf, Kbf, (void*)Sb, nullptr, 1.0f,
        DMODEL, DMODEL, SEQ, DMODEL / 32,
        (size_t)SEQ * DMODEL, (size_t)SEQ * DMODEL, (size_t)SEQ * SEQ);
    // in-place row softmax -> P, Linv
    softmax_rows<<<dim3(BATCH * SEQ), 256, 0, stream>>>(Sb, Linv);
    // Z[b][q][e] = (P[b] . V[b]) * Linv  (f32 store), batch on x again
    gemm256<2, 1><<<dim3(8, 8, 4), 512, 0, stream>>>(
        Sb, VTb, (void*)out, Linv, 1.0f,
        SEQ, SEQ, DMODEL, SEQ / 32,
        (size_t)SEQ * SEQ, (size_t)DMODEL * SEQ, (size_t)SEQ * DMODEL);
}